// Round 7
// baseline (235.872 us; speedup 1.0000x reference)
//
#include <hip/hip_runtime.h>

// -------------------------------------------------------------------------
// GCN: h1 = relu(Agg(x@W1)+b1); h2 = relu(Agg(h1@W2)+b2); out = h2@Wl+bl
// R19 = exact R16 base (228.8us best) + ONE change: gemm N-split.
//   - gemm3: NT=4 tiles with blockIdx.y column offset (2 y-blocks for the
//     128-col gemms). LDS 64KB->32KB, acc VGPR 64->32 -> 3 blocks/CU
//     (was 2), grid 391->782 -> inter-block pipelining instead of one
//     serialized resident block per CU slot. B staging traffic unchanged;
//     A tile read 2x (L3-resident). Bit-identical outputs.
// Post-mortems: R18 (padded CSR + fp32 agg out) = +3.4us, reverted: agg is
//   NOT bound on clamp/pack VALU; R17 planes = +22.7 (4x fixed cost), but
//   exposed agg counters: VALUBusy~70%, HBM 14%, gathers cache-absorbed.
// R16: v_pk_add_f32 agg accumulation. R15/R14: swapped-operand MFMA C^T
//   epilogue (packed stores); u16 edges; prepW fused into count; dinv in
//   scan1. Blo stays in LDS (R13: global B on MFMA path = -5us).
// Carried: bf16x3-split MFMA, XOR-swizzled LDS B, A prefetch, dinv
//   row-scaling fused in gemm, rank-capture CSR build, atomic-free place.
// Failed & reverted: grid barrier, node/feature XCD sharding (R9/R17),
//   fat-kernel overlap, merged scan, Blo streaming (R13), padded-CSR+
//   fp32-agg-out (R18).
// -------------------------------------------------------------------------

typedef __attribute__((ext_vector_type(8))) __bf16 bf16x8;
typedef __attribute__((ext_vector_type(8))) short short8;
typedef __attribute__((ext_vector_type(4))) float f32x4;
typedef __attribute__((ext_vector_type(2))) float f32x2;

__device__ inline float bf_lo(unsigned u) { return __uint_as_float(u << 16); }
__device__ inline float bf_hi(unsigned u) { return __uint_as_float(u & 0xffff0000u); }
__device__ inline unsigned short f2bf(float v) {
  return __builtin_bit_cast(unsigned short, (__bf16)v);
}
// packed 2xf32 add (VOP3P)
__device__ inline f32x2 pkadd(f32x2 a, f32x2 b) {
  f32x2 d;
  asm("v_pk_add_f32 %0, %1, %2" : "=v"(d) : "v"(a), "v"(b));
  return d;
}
// bf16 pair word -> float2 {low half, high half}
__device__ inline f32x2 bfpair(unsigned w) {
  f32x2 r;
  r.x = __uint_as_float(w << 16);
  r.y = __uint_as_float(w & 0xffff0000u);
  return r;
}

// fat kernel: blocks [0, nbe) count in-degrees + capture rank;
// blocks [nbe, nbe+160) split/transpose weights to bf16 hi/lo
__global__ void k_count_prepW(const int* __restrict__ dst, int E, int nbe,
                              int* __restrict__ cnt, int* __restrict__ rank,
                              const float* __restrict__ W1, const float* __restrict__ W2,
                              const float* __restrict__ Wl,
                              unsigned short* __restrict__ b1h, unsigned short* __restrict__ b1l,
                              unsigned short* __restrict__ b2h, unsigned short* __restrict__ b2l,
                              unsigned short* __restrict__ blh, unsigned short* __restrict__ bll) {
  if ((int)blockIdx.x < nbe) {
    int i = blockIdx.x * 256 + threadIdx.x;
    if (i < E) rank[i] = atomicAdd(&cnt[dst[i]], 1);
  } else {
    int idx = ((int)blockIdx.x - nbe) * 256 + threadIdx.x;
    const float* W;
    unsigned short *bh, *bl_;
    int N, local;
    if (idx < 16384)      { W = W1; bh = b1h; bl_ = b1l; N = 128; local = idx; }
    else if (idx < 32768) { W = W2; bh = b2h; bl_ = b2l; N = 128; local = idx - 16384; }
    else if (idx < 40960) { W = Wl; bh = blh; bl_ = bll; N = 64;  local = idx - 32768; }
    else return;
    int nn = local >> 7, k = local & 127;
    float v = W[(size_t)k * N + nn];
    __bf16 h = (__bf16)v;
    bh[local] = __builtin_bit_cast(unsigned short, h);
    bl_[local] = f2bf(v - (float)h);
  }
}

// scan1: per-block partial sums of cnt; also dinv = rsqrt(deg+1)
__global__ void k_scan1(const int* __restrict__ cnt, int n, int* __restrict__ partial,
                        float* __restrict__ dinv) {
  __shared__ int s[256];
  int i = blockIdx.x * 256 + threadIdx.x;
  int v = (i < n) ? cnt[i] : 0;
  s[threadIdx.x] = v;
  if (i < n) dinv[i] = rsqrtf((float)(v + 1));
  __syncthreads();
  for (int off = 128; off > 0; off >>= 1) {
    if (threadIdx.x < off) s[threadIdx.x] += s[threadIdx.x + off];
    __syncthreads();
  }
  if (threadIdx.x == 0) partial[blockIdx.x] = s[0];
}

// scan3: block base from partials + exclusive scan -> row_off
__global__ void k_scan3(const int* __restrict__ cnt, const int* __restrict__ partial,
                        int nb, int n, int* __restrict__ row_off) {
  __shared__ int s[256];
  __shared__ int base_s;
  int t = threadIdx.x;
  s[t] = (t < nb && t < (int)blockIdx.x) ? partial[t] : 0;
  __syncthreads();
  for (int off = 128; off > 0; off >>= 1) {
    if (t < off) s[t] += s[t + off];
    __syncthreads();
  }
  if (t == 0) base_s = s[0];
  __syncthreads();
  int base = base_s;
  __syncthreads();

  int i = blockIdx.x * 256 + t;
  int v = (i < n) ? cnt[i] : 0;
  s[t] = v;
  __syncthreads();
  for (int off = 1; off < 256; off <<= 1) {
    int u = (t >= off) ? s[t - off] : 0;
    __syncthreads();
    s[t] += u;
    __syncthreads();
  }
  int incl = s[t];
  int excl = incl - v;
  if (i < n) {
    row_off[i] = base + excl;
    if (i == n - 1) row_off[n] = base + incl;
  }
}

// place: NO atomics -- pos = row_off[dst] + rank; edges stored as u16
__global__ void k_place(const int* __restrict__ src, const int* __restrict__ dst,
                        const int* __restrict__ rank, const int* __restrict__ row_off,
                        int E, unsigned short* __restrict__ edges) {
  int e = blockIdx.x * blockDim.x + threadIdx.x;
  if (e < E) {
    int d = dst[e];
    int pos = row_off[d] + rank[e];
    __builtin_nontemporal_store((unsigned short)src[e], &edges[pos]);
  }
}

// ------------------- MFMA GEMM: A prefetched, B (hi+lo) in LDS -----------
// C[M x NFULL] = A[M x 128] @ B[128 x NFULL]; this block computes NT*16
// cols at offset co = blockIdx.y * NT*16. NT=4 -> LDS 32KB, 3 blocks/CU.
// Operand-SWAPPED mfma: acc = mfma(b_frag, a_frag, acc) computes C^T tile
// layout: per lane, C-row = m_base+mt*16+lm, C-cols = co+nt*16+lk*4+r
// -> packed 8B/16B epilogue stores.
// SCALE: multiply output row r by dinv[r] and write zero row M (agg OOB).
template <int NT, int NFULL, bool A32, bool BIAS, bool OUT_BF16, bool SCALE>
__global__ __launch_bounds__(256) void gemm3(
    const void* __restrict__ Ahi_, const unsigned short* __restrict__ Alo,
    const unsigned short* __restrict__ Bhi, const unsigned short* __restrict__ Blo,
    const float* __restrict__ bias, const float* __restrict__ dinv,
    void* __restrict__ Cout, int M) {
  constexpr int K = 128;
  constexpr int NCOL = NT * 16;
  __shared__ alignas(16) unsigned short lbh[NCOL * K];
  __shared__ alignas(16) unsigned short lbl[NCOL * K];
  int t = threadIdx.x;
  int lane = t & 63, wave = t >> 6;
  int lm = lane & 15, lk = lane >> 4;
  int m_base = blockIdx.x * 128 + wave * 32;
  int co = blockIdx.y * NCOL;   // column offset within NFULL
  const short8 zero8 = {0, 0, 0, 0, 0, 0, 0, 0};

  if (SCALE && blockIdx.x == 0 && blockIdx.y == 0 && t < 64) {
    // zero row M for agg OOB lanes (covers all NFULL=128 u16: 64 x 4B)
    *(unsigned*)&((unsigned short*)Cout)[(size_t)M * NFULL + t * 2] = 0u;
  }

  // ---- phase 1: prefetch all A fragments ----
  bf16x8 ah[2][4], al[2][4];
  if (A32) {
    const float* Af = (const float*)Ahi_;
    float4 ra[2][4][2];
#pragma unroll
    for (int mt = 0; mt < 2; ++mt) {
      int row = m_base + mt * 16 + lm;
#pragma unroll
      for (int ks = 0; ks < 4; ++ks) {
        if (row < M) {
          ra[mt][ks][0] = *(const float4*)&Af[(size_t)row * K + ks * 32 + lk * 8];
          ra[mt][ks][1] = *(const float4*)&Af[(size_t)row * K + ks * 32 + lk * 8 + 4];
        } else {
          ra[mt][ks][0] = make_float4(0.f, 0.f, 0.f, 0.f);
          ra[mt][ks][1] = make_float4(0.f, 0.f, 0.f, 0.f);
        }
      }
    }
#pragma unroll
    for (int mt = 0; mt < 2; ++mt)
#pragma unroll
      for (int ks = 0; ks < 4; ++ks) {
        float av[8] = {ra[mt][ks][0].x, ra[mt][ks][0].y, ra[mt][ks][0].z, ra[mt][ks][0].w,
                       ra[mt][ks][1].x, ra[mt][ks][1].y, ra[mt][ks][1].z, ra[mt][ks][1].w};
#pragma unroll
        for (int j = 0; j < 8; ++j) {
          __bf16 h = (__bf16)av[j];
          ah[mt][ks][j] = h;
          al[mt][ks][j] = (__bf16)(av[j] - (float)h);
        }
      }
  } else {
    const unsigned short* Ahi = (const unsigned short*)Ahi_;
#pragma unroll
    for (int mt = 0; mt < 2; ++mt) {
      int row = m_base + mt * 16 + lm;
#pragma unroll
      for (int ks = 0; ks < 4; ++ks) {
        if (row < M) {
          ah[mt][ks] = *(const bf16x8*)&Ahi[(size_t)row * K + ks * 32 + lk * 8];
          al[mt][ks] = *(const bf16x8*)&Alo[(size_t)row * K + ks * 32 + lk * 8];
        } else {
          ah[mt][ks] = __builtin_bit_cast(bf16x8, zero8);
          al[mt][ks] = __builtin_bit_cast(bf16x8, zero8);
        }
      }
    }
  }

  // ---- phase 2: cooperative B staging (XOR-swizzled 16B chunks) ----
  for (int c = t; c < NCOL * 16; c += 256) {
    int r = c >> 4, q = c & 15;
    int sq = q ^ (r & 15);
    *(short8*)&lbh[r * K + sq * 8] = *(const short8*)&Bhi[(size_t)(co + r) * K + q * 8];
    *(short8*)&lbl[r * K + sq * 8] = *(const short8*)&Blo[(size_t)(co + r) * K + q * 8];
  }
  __syncthreads();

  // ---- phase 3: pure LDS + MFMA, swapped operands ----
  f32x4 acc[2][NT] = {};
#pragma unroll
  for (int ks = 0; ks < 4; ++ks) {
    int chunk = ks * 4 + lk;
    bf16x8 bh[NT], bl[NT];
#pragma unroll
    for (int nt = 0; nt < NT; ++nt) {
      int r = nt * 16 + lm;
      int sq = chunk ^ lm;
      bh[nt] = *(const bf16x8*)&lbh[r * K + sq * 8];
      bl[nt] = *(const bf16x8*)&lbl[r * K + sq * 8];
    }
#pragma unroll
    for (int mt = 0; mt < 2; ++mt)
#pragma unroll
      for (int nt = 0; nt < NT; ++nt) {
        acc[mt][nt] = __builtin_amdgcn_mfma_f32_16x16x32_bf16(bh[nt], ah[mt][ks], acc[mt][nt], 0, 0, 0);
        acc[mt][nt] = __builtin_amdgcn_mfma_f32_16x16x32_bf16(bl[nt], ah[mt][ks], acc[mt][nt], 0, 0, 0);
        acc[mt][nt] = __builtin_amdgcn_mfma_f32_16x16x32_bf16(bh[nt], al[mt][ks], acc[mt][nt], 0, 0, 0);
      }
  }

  // ---- epilogue (transposed acc): row = m_base+mt*16+lm, cols = co+nt*16+lk*4+r
#pragma unroll
  for (int mt = 0; mt < 2; ++mt) {
    int row = m_base + mt * 16 + lm;
    if (row < M) {
      float dr = SCALE ? dinv[row] : 1.f;
#pragma unroll
      for (int nt = 0; nt < NT; ++nt) {
        int col0 = co + nt * 16 + lk * 4;
        float v0 = acc[mt][nt][0], v1 = acc[mt][nt][1];
        float v2 = acc[mt][nt][2], v3 = acc[mt][nt][3];
        if (SCALE) { v0 *= dr; v1 *= dr; v2 *= dr; v3 *= dr; }
        if (BIAS) {
          float4 bb = *(const float4*)&bias[col0];
          v0 += bb.x; v1 += bb.y; v2 += bb.z; v3 += bb.w;
        }
        if (OUT_BF16) {
          unsigned p0 = (unsigned)f2bf(v0) | ((unsigned)f2bf(v1) << 16);
          unsigned p1 = (unsigned)f2bf(v2) | ((unsigned)f2bf(v3) << 16);
          uint2 pk = make_uint2(p0, p1);
          *(uint2*)&((unsigned short*)Cout)[(size_t)row * NFULL + col0] = pk;
        } else {
          float4 pk = make_float4(v0, v1, v2, v3);
          *(float4*)&((float*)Cout)[(size_t)row * NFULL + col0] = pk;
        }
      }
    }
  }
}

// ------------------- aggregation: 16 edges in flight, u16 edges ----------
// rows pre-scaled by dinv[src]; agg_i = dinv_i*(sum + self) + bias, relu.
// OOB edge slots read zero row M (index n).
// Hot loop accumulates in float2 via v_pk_add_f32.
__global__ __launch_bounds__(256) void k_agg(const unsigned short* __restrict__ t,
                      const int* __restrict__ row_off,
                      const unsigned short* __restrict__ edges,
                      const float* __restrict__ dinv, const float* __restrict__ bias,
                      unsigned short* __restrict__ ghi, unsigned short* __restrict__ glo,
                      int n) {
  int wave = threadIdx.x >> 6;
  int lane = threadIdx.x & 63;
  int g = lane >> 4;
  int fl = lane & 15;          // features fl*8 .. fl*8+7
  int node = blockIdx.x * 4 + wave;
  if (node >= n) return;
  int2 ro = *(const int2*)&row_off[node];
  int e0 = ro.x, e1 = ro.y;
  int last = e1 - 1;

  // hoisted epilogue loads: overlap with gather chain
  float di = dinv[node];
  uint4 sv = *(const uint4*)&t[(size_t)node * 128 + fl * 8];
  float4 bb0 = *(const float4*)&bias[fl * 8];
  float4 bb1 = *(const float4*)&bias[fl * 8 + 4];

  f32x2 acc2[4] = {};
  for (int base = e0; base < e1; base += 16) {
    int i0 = base + g, i1 = i0 + 4, i2 = i0 + 8, i3 = i0 + 12;
    int s0 = edges[i0 < e1 ? i0 : last];
    int s1 = edges[i1 < e1 ? i1 : last];
    int s2 = edges[i2 < e1 ? i2 : last];
    int s3 = edges[i3 < e1 ? i3 : last];
    s0 = i0 < e1 ? s0 : n;     // zero row
    s1 = i1 < e1 ? s1 : n;
    s2 = i2 < e1 ? s2 : n;
    s3 = i3 < e1 ? s3 : n;
    uint4 u0 = *(const uint4*)&t[(size_t)s0 * 128 + fl * 8];
    uint4 u1 = *(const uint4*)&t[(size_t)s1 * 128 + fl * 8];
    uint4 u2 = *(const uint4*)&t[(size_t)s2 * 128 + fl * 8];
    uint4 u3 = *(const uint4*)&t[(size_t)s3 * 128 + fl * 8];
    acc2[0] = pkadd(acc2[0], pkadd(pkadd(bfpair(u0.x), bfpair(u1.x)),
                                   pkadd(bfpair(u2.x), bfpair(u3.x))));
    acc2[1] = pkadd(acc2[1], pkadd(pkadd(bfpair(u0.y), bfpair(u1.y)),
                                   pkadd(bfpair(u2.y), bfpair(u3.y))));
    acc2[2] = pkadd(acc2[2], pkadd(pkadd(bfpair(u0.z), bfpair(u1.z)),
                                   pkadd(bfpair(u2.z), bfpair(u3.z))));
    acc2[3] = pkadd(acc2[3], pkadd(pkadd(bfpair(u0.w), bfpair(u1.w)),
                                   pkadd(bfpair(u2.w), bfpair(u3.w))));
  }
  float acc[8];
#pragma unroll
  for (int j = 0; j < 4; ++j) { acc[2 * j] = acc2[j].x; acc[2 * j + 1] = acc2[j].y; }
#pragma unroll
  for (int j = 0; j < 8; ++j) {
    acc[j] += __shfl_xor(acc[j], 16);
    acc[j] += __shfl_xor(acc[j], 32);
  }
  if (g == 0) {
    acc[0] += bf_lo(sv.x); acc[1] += bf_hi(sv.x);
    acc[2] += bf_lo(sv.y); acc[3] += bf_hi(sv.y);
    acc[4] += bf_lo(sv.z); acc[5] += bf_hi(sv.z);
    acc[6] += bf_lo(sv.w); acc[7] += bf_hi(sv.w);
    float bb[8] = {bb0.x, bb0.y, bb0.z, bb0.w, bb1.x, bb1.y, bb1.z, bb1.w};
    short8 ho, lo_;
#pragma unroll
    for (int j = 0; j < 8; ++j) {
      float s = fmaxf(acc[j] * di + bb[j], 0.f);
      __bf16 h = (__bf16)s;
      ho[j] = __builtin_bit_cast(short, h);
      lo_[j] = (short)f2bf(s - (float)h);
    }
    *(short8*)&ghi[(size_t)node * 128 + fl * 8] = ho;
    *(short8*)&glo[(size_t)node * 128 + fl * 8] = lo_;
  }
}

extern "C" void kernel_launch(void* const* d_in, const int* in_sizes, int n_in,
                              void* d_out, int out_size, void* d_ws, size_t ws_size,
                              hipStream_t stream) {
  const float* x  = (const float*)d_in[0];
  const int*   ei = (const int*)d_in[1];
  const float* W1 = (const float*)d_in[2];
  const float* b1 = (const float*)d_in[3];
  const float* W2 = (const float*)d_in[4];
  const float* b2 = (const float*)d_in[5];
  const float* Wl = (const float*)d_in[6];
  const float* bl = (const float*)d_in[7];
  float* out = (float*)d_out;

  const int D = 128;
  int N = in_sizes[0] / D;
  int E = in_sizes[1] / 2;
  const int* src = ei;
  const int* dst = ei + E;

  uintptr_t ws = (uintptr_t)d_ws;
  auto take = [&](size_t bytes) {
    uintptr_t p = ws;
    ws += (bytes + 15) & ~(size_t)15;
    return p;
  };
  unsigned short* t_bf = (unsigned short*)take(((size_t)N + 1) * D * 2);  // + zero row
  unsigned short* xh   = (unsigned short*)take((size_t)N * D * 2);
  unsigned short* xl   = (unsigned short*)take((size_t)N * D * 2);
  unsigned short* edges = (unsigned short*)take((size_t)E * 2);  // u16 src ids
  int*   rank    = (int*)take((size_t)E * 4);
  int*   cnt     = (int*)take((size_t)N * sizeof(int));
  int*   row_off = (int*)take(((size_t)N + 1) * sizeof(int));
  float* dinv    = (float*)take((size_t)N * sizeof(float));
  int*   partial = (int*)take(256 * sizeof(int));
  unsigned short* b1h = (unsigned short*)take(128 * 128 * 2);
  unsigned short* b1l = (unsigned short*)take(128 * 128 * 2);
  unsigned short* b2h = (unsigned short*)take(128 * 128 * 2);
  unsigned short* b2l = (unsigned short*)take(128 * 128 * 2);
  unsigned short* blh = (unsigned short*)take(128 * 64 * 2);
  unsigned short* bll = (unsigned short*)take(128 * 64 * 2);

  int nb_n = (N + 255) / 256;   // 196 (fits single-block base reduce)
  int nb_e = (E + 255) / 256;

  // ---- graph preprocessing + weight prep ----
  hipMemsetAsync(cnt, 0, (size_t)N * sizeof(int), stream);
  k_count_prepW<<<nb_e + 160, 256, 0, stream>>>(dst, E, nb_e, cnt, rank,
                                                W1, W2, Wl, b1h, b1l, b2h, b2l, blh, bll);
  k_scan1<<<nb_n, 256, 0, stream>>>(cnt, N, partial, dinv);
  k_scan3<<<nb_n, 256, 0, stream>>>(cnt, partial, nb_n, N, row_off);
  k_place<<<nb_e, 256, 0, stream>>>(src, dst, rank, row_off, E, edges);

  int gemm_blocks = (N + 127) / 128;
  int agg_blocks = (N + 3) / 4;

  // ---- layer 1 (A = fp32 x, split in-register; output pre-scaled by dinv) ----
  gemm3<4, 128, true, false, true, true><<<dim3(gemm_blocks, 2), 256, 0, stream>>>(
      x, nullptr, b1h, b1l, nullptr, dinv, t_bf, N);
  k_agg<<<agg_blocks, 256, 0, stream>>>(t_bf, row_off, edges, dinv, b1, xh, xl, N);
  // ---- layer 2 ----
  gemm3<4, 128, false, false, true, true><<<dim3(gemm_blocks, 2), 256, 0, stream>>>(
      xh, xl, b2h, b2l, nullptr, dinv, t_bf, N);
  k_agg<<<agg_blocks, 256, 0, stream>>>(t_bf, row_off, edges, dinv, b2, xh, xl, N);
  // ---- classifier ----
  gemm3<4, 64, false, true, false, false><<<dim3(gemm_blocks, 1), 256, 0, stream>>>(
      xh, xl, blh, bll, bl, nullptr, out, N);
}

// Round 8
// 235.609 us; speedup vs baseline: 1.0011x; 1.0011x over previous
//
#include <hip/hip_runtime.h>

// -------------------------------------------------------------------------
// GCN: h1 = relu(Agg(x@W1)+b1); h2 = relu(Agg(h1@W2)+b2); out = h2@Wl+bl
// R20 = exact R16 base (228.8us best) + ONE change: k_agg processes 2 nodes
// per wave (dual independent gather chains, 8 useful loads in flight/wave).
//   Mechanism probe: per-wave MLP. R16 wave = 1 node (avg deg 12.8) -> ~4
//   gathers in flight then full L2/L3 latency stall. Two nodes/wave doubles
//   in-flight useful gathers; wave count halves; per-node math/reduce order
//   IDENTICAL -> bit-identical outputs (absmax must stay 0.0004882812).
//   Epilogue parallel: g==0 lanes write nodeA, g==1 write nodeB.
// Falsified this session (all reverted): R17 feature-quarter planes (+22.7,
//   4x fixed cost; exposed agg counters: VALUBusy~70%, HBM 14%, gathers
//   cache-absorbed), R18 branchless padded CSR + fp32 agg out (+3.4: agg
//   NOT instruction-count-bound), R19 gemm N-split (+7.1: gemm blocks not
//   latency-serialized).
// R16: v_pk_add_f32 agg accumulation. R15/R14: swapped-operand MFMA C^T
//   epilogue (packed stores); u16 edges; prepW fused into count; dinv in
//   scan1. Blo stays in LDS (R13: global B on MFMA path = -5us).
// Carried: bf16x3-split MFMA, XOR-swizzled LDS B, A prefetch, dinv
//   row-scaling fused in gemm, rank-capture CSR build, atomic-free place.
// -------------------------------------------------------------------------

typedef __attribute__((ext_vector_type(8))) __bf16 bf16x8;
typedef __attribute__((ext_vector_type(8))) short short8;
typedef __attribute__((ext_vector_type(4))) float f32x4;
typedef __attribute__((ext_vector_type(2))) float f32x2;

__device__ inline float bf_lo(unsigned u) { return __uint_as_float(u << 16); }
__device__ inline float bf_hi(unsigned u) { return __uint_as_float(u & 0xffff0000u); }
__device__ inline unsigned short f2bf(float v) {
  return __builtin_bit_cast(unsigned short, (__bf16)v);
}
// packed 2xf32 add (VOP3P)
__device__ inline f32x2 pkadd(f32x2 a, f32x2 b) {
  f32x2 d;
  asm("v_pk_add_f32 %0, %1, %2" : "=v"(d) : "v"(a), "v"(b));
  return d;
}
// bf16 pair word -> float2 {low half, high half}
__device__ inline f32x2 bfpair(unsigned w) {
  f32x2 r;
  r.x = __uint_as_float(w << 16);
  r.y = __uint_as_float(w & 0xffff0000u);
  return r;
}

// fat kernel: blocks [0, nbe) count in-degrees + capture rank;
// blocks [nbe, nbe+160) split/transpose weights to bf16 hi/lo
__global__ void k_count_prepW(const int* __restrict__ dst, int E, int nbe,
                              int* __restrict__ cnt, int* __restrict__ rank,
                              const float* __restrict__ W1, const float* __restrict__ W2,
                              const float* __restrict__ Wl,
                              unsigned short* __restrict__ b1h, unsigned short* __restrict__ b1l,
                              unsigned short* __restrict__ b2h, unsigned short* __restrict__ b2l,
                              unsigned short* __restrict__ blh, unsigned short* __restrict__ bll) {
  if ((int)blockIdx.x < nbe) {
    int i = blockIdx.x * 256 + threadIdx.x;
    if (i < E) rank[i] = atomicAdd(&cnt[dst[i]], 1);
  } else {
    int idx = ((int)blockIdx.x - nbe) * 256 + threadIdx.x;
    const float* W;
    unsigned short *bh, *bl_;
    int N, local;
    if (idx < 16384)      { W = W1; bh = b1h; bl_ = b1l; N = 128; local = idx; }
    else if (idx < 32768) { W = W2; bh = b2h; bl_ = b2l; N = 128; local = idx - 16384; }
    else if (idx < 40960) { W = Wl; bh = blh; bl_ = bll; N = 64;  local = idx - 32768; }
    else return;
    int nn = local >> 7, k = local & 127;
    float v = W[(size_t)k * N + nn];
    __bf16 h = (__bf16)v;
    bh[local] = __builtin_bit_cast(unsigned short, h);
    bl_[local] = f2bf(v - (float)h);
  }
}

// scan1: per-block partial sums of cnt; also dinv = rsqrt(deg+1)
__global__ void k_scan1(const int* __restrict__ cnt, int n, int* __restrict__ partial,
                        float* __restrict__ dinv) {
  __shared__ int s[256];
  int i = blockIdx.x * 256 + threadIdx.x;
  int v = (i < n) ? cnt[i] : 0;
  s[threadIdx.x] = v;
  if (i < n) dinv[i] = rsqrtf((float)(v + 1));
  __syncthreads();
  for (int off = 128; off > 0; off >>= 1) {
    if (threadIdx.x < off) s[threadIdx.x] += s[threadIdx.x + off];
    __syncthreads();
  }
  if (threadIdx.x == 0) partial[blockIdx.x] = s[0];
}

// scan3: block base from partials + exclusive scan -> row_off
__global__ void k_scan3(const int* __restrict__ cnt, const int* __restrict__ partial,
                        int nb, int n, int* __restrict__ row_off) {
  __shared__ int s[256];
  __shared__ int base_s;
  int t = threadIdx.x;
  s[t] = (t < nb && t < (int)blockIdx.x) ? partial[t] : 0;
  __syncthreads();
  for (int off = 128; off > 0; off >>= 1) {
    if (t < off) s[t] += s[t + off];
    __syncthreads();
  }
  if (t == 0) base_s = s[0];
  __syncthreads();
  int base = base_s;
  __syncthreads();

  int i = blockIdx.x * 256 + t;
  int v = (i < n) ? cnt[i] : 0;
  s[t] = v;
  __syncthreads();
  for (int off = 1; off < 256; off <<= 1) {
    int u = (t >= off) ? s[t - off] : 0;
    __syncthreads();
    s[t] += u;
    __syncthreads();
  }
  int incl = s[t];
  int excl = incl - v;
  if (i < n) {
    row_off[i] = base + excl;
    if (i == n - 1) row_off[n] = base + incl;
  }
}

// place: NO atomics -- pos = row_off[dst] + rank; edges stored as u16
__global__ void k_place(const int* __restrict__ src, const int* __restrict__ dst,
                        const int* __restrict__ rank, const int* __restrict__ row_off,
                        int E, unsigned short* __restrict__ edges) {
  int e = blockIdx.x * blockDim.x + threadIdx.x;
  if (e < E) {
    int d = dst[e];
    int pos = row_off[d] + rank[e];
    __builtin_nontemporal_store((unsigned short)src[e], &edges[pos]);
  }
}

// ------------------- MFMA GEMM: A prefetched, B (hi+lo) in LDS -----------
// C[M x N] = A[M x 128] @ B[128 x N], N = NT*16.
// Operand-SWAPPED mfma: acc = mfma(b_frag, a_frag, acc) computes C^T tile
// layout: per lane, C-row = m_base+mt*16+lm, C-cols = nt*16+lk*4+r (r=0..3)
// -> packed 8B/16B epilogue stores.
// SCALE: multiply output row r by dinv[r] and write zero row M (agg OOB).
template <int NT, bool A32, bool BIAS, bool OUT_BF16, bool SCALE>
__global__ __launch_bounds__(256) void gemm3(
    const void* __restrict__ Ahi_, const unsigned short* __restrict__ Alo,
    const unsigned short* __restrict__ Bhi, const unsigned short* __restrict__ Blo,
    const float* __restrict__ bias, const float* __restrict__ dinv,
    void* __restrict__ Cout, int M) {
  constexpr int K = 128;
  constexpr int NCOL = NT * 16;
  __shared__ alignas(16) unsigned short lbh[NCOL * K];
  __shared__ alignas(16) unsigned short lbl[NCOL * K];
  int t = threadIdx.x;
  int lane = t & 63, wave = t >> 6;
  int lm = lane & 15, lk = lane >> 4;
  int m_base = blockIdx.x * 128 + wave * 32;
  const short8 zero8 = {0, 0, 0, 0, 0, 0, 0, 0};

  if (SCALE && blockIdx.x == 0 && t < 64) {   // zero row M for agg OOB lanes
    *(unsigned*)&((unsigned short*)Cout)[(size_t)M * NCOL + t * 2] = 0u;
  }

  // ---- phase 1: prefetch all A fragments ----
  bf16x8 ah[2][4], al[2][4];
  if (A32) {
    const float* Af = (const float*)Ahi_;
    float4 ra[2][4][2];
#pragma unroll
    for (int mt = 0; mt < 2; ++mt) {
      int row = m_base + mt * 16 + lm;
#pragma unroll
      for (int ks = 0; ks < 4; ++ks) {
        if (row < M) {
          ra[mt][ks][0] = *(const float4*)&Af[(size_t)row * K + ks * 32 + lk * 8];
          ra[mt][ks][1] = *(const float4*)&Af[(size_t)row * K + ks * 32 + lk * 8 + 4];
        } else {
          ra[mt][ks][0] = make_float4(0.f, 0.f, 0.f, 0.f);
          ra[mt][ks][1] = make_float4(0.f, 0.f, 0.f, 0.f);
        }
      }
    }
#pragma unroll
    for (int mt = 0; mt < 2; ++mt)
#pragma unroll
      for (int ks = 0; ks < 4; ++ks) {
        float av[8] = {ra[mt][ks][0].x, ra[mt][ks][0].y, ra[mt][ks][0].z, ra[mt][ks][0].w,
                       ra[mt][ks][1].x, ra[mt][ks][1].y, ra[mt][ks][1].z, ra[mt][ks][1].w};
#pragma unroll
        for (int j = 0; j < 8; ++j) {
          __bf16 h = (__bf16)av[j];
          ah[mt][ks][j] = h;
          al[mt][ks][j] = (__bf16)(av[j] - (float)h);
        }
      }
  } else {
    const unsigned short* Ahi = (const unsigned short*)Ahi_;
#pragma unroll
    for (int mt = 0; mt < 2; ++mt) {
      int row = m_base + mt * 16 + lm;
#pragma unroll
      for (int ks = 0; ks < 4; ++ks) {
        if (row < M) {
          ah[mt][ks] = *(const bf16x8*)&Ahi[(size_t)row * K + ks * 32 + lk * 8];
          al[mt][ks] = *(const bf16x8*)&Alo[(size_t)row * K + ks * 32 + lk * 8];
        } else {
          ah[mt][ks] = __builtin_bit_cast(bf16x8, zero8);
          al[mt][ks] = __builtin_bit_cast(bf16x8, zero8);
        }
      }
    }
  }

  // ---- phase 2: cooperative B staging (XOR-swizzled 16B chunks) ----
  for (int c = t; c < NCOL * 16; c += 256) {
    int r = c >> 4, q = c & 15;
    int sq = q ^ (r & 15);
    *(short8*)&lbh[r * K + sq * 8] = *(const short8*)&Bhi[r * K + q * 8];
    *(short8*)&lbl[r * K + sq * 8] = *(const short8*)&Blo[r * K + q * 8];
  }
  __syncthreads();

  // ---- phase 3: pure LDS + MFMA, swapped operands ----
  f32x4 acc[2][NT] = {};
#pragma unroll
  for (int ks = 0; ks < 4; ++ks) {
    int chunk = ks * 4 + lk;
    bf16x8 bh[NT], bl[NT];
#pragma unroll
    for (int nt = 0; nt < NT; ++nt) {
      int r = nt * 16 + lm;
      int sq = chunk ^ lm;
      bh[nt] = *(const bf16x8*)&lbh[r * K + sq * 8];
      bl[nt] = *(const bf16x8*)&lbl[r * K + sq * 8];
    }
#pragma unroll
    for (int mt = 0; mt < 2; ++mt)
#pragma unroll
      for (int nt = 0; nt < NT; ++nt) {
        acc[mt][nt] = __builtin_amdgcn_mfma_f32_16x16x32_bf16(bh[nt], ah[mt][ks], acc[mt][nt], 0, 0, 0);
        acc[mt][nt] = __builtin_amdgcn_mfma_f32_16x16x32_bf16(bl[nt], ah[mt][ks], acc[mt][nt], 0, 0, 0);
        acc[mt][nt] = __builtin_amdgcn_mfma_f32_16x16x32_bf16(bh[nt], al[mt][ks], acc[mt][nt], 0, 0, 0);
      }
  }

  // ---- epilogue (transposed acc): row = m_base+mt*16+lm, cols = nt*16+lk*4+r
#pragma unroll
  for (int mt = 0; mt < 2; ++mt) {
    int row = m_base + mt * 16 + lm;
    if (row < M) {
      float dr = SCALE ? dinv[row] : 1.f;
#pragma unroll
      for (int nt = 0; nt < NT; ++nt) {
        int col0 = nt * 16 + lk * 4;
        float v0 = acc[mt][nt][0], v1 = acc[mt][nt][1];
        float v2 = acc[mt][nt][2], v3 = acc[mt][nt][3];
        if (SCALE) { v0 *= dr; v1 *= dr; v2 *= dr; v3 *= dr; }
        if (BIAS) {
          float4 bb = *(const float4*)&bias[col0];
          v0 += bb.x; v1 += bb.y; v2 += bb.z; v3 += bb.w;
        }
        if (OUT_BF16) {
          unsigned p0 = (unsigned)f2bf(v0) | ((unsigned)f2bf(v1) << 16);
          unsigned p1 = (unsigned)f2bf(v2) | ((unsigned)f2bf(v3) << 16);
          uint2 pk = make_uint2(p0, p1);
          *(uint2*)&((unsigned short*)Cout)[(size_t)row * NCOL + col0] = pk;
        } else {
          float4 pk = make_float4(v0, v1, v2, v3);
          *(float4*)&((float*)Cout)[(size_t)row * NCOL + col0] = pk;
        }
      }
    }
  }
}

// ------------------- aggregation: 2 nodes/wave, dual gather chains -------
// Wave handles nodeA=2w, nodeB=2w+1. Per iter: A's 4 gathers + B's 4
// gathers in flight (independent chains). Per-node grouping / pkadd tree /
// butterfly identical to R16 -> bit-identical outputs.
// Epilogue: g==0 lanes write nodeA, g==1 lanes write nodeB (sums are in
// all lanes after xor16/32 butterfly).
__global__ __launch_bounds__(256) void k_agg(const unsigned short* __restrict__ t,
                      const int* __restrict__ row_off,
                      const unsigned short* __restrict__ edges,
                      const float* __restrict__ dinv, const float* __restrict__ bias,
                      unsigned short* __restrict__ ghi, unsigned short* __restrict__ glo,
                      int n) {
  int wave = threadIdx.x >> 6;
  int lane = threadIdx.x & 63;
  int g = lane >> 4;
  int fl = lane & 15;          // features fl*8 .. fl*8+7
  int nodeA = blockIdx.x * 8 + wave * 2;
  if (nodeA >= n) return;
  int nodeB = nodeA + 1;
  bool hasB = nodeB < n;
  int e0A = row_off[nodeA];
  int e1A = row_off[nodeA + 1];
  int e1B = hasB ? row_off[nodeB + 1] : e1A;   // empty range if no B
  int e0B = e1A;
  int lastA = e1A - 1, lastB = e1B - 1;

  // hoisted per-lane epilogue loads: g==1 lanes take nodeB's self/dinv
  int nodeS = (g == 1 && hasB) ? nodeB : nodeA;
  float di = dinv[nodeS];
  uint4 sv = *(const uint4*)&t[(size_t)nodeS * 128 + fl * 8];
  float4 bb0 = *(const float4*)&bias[fl * 8];
  float4 bb1 = *(const float4*)&bias[fl * 8 + 4];

  f32x2 aA[4] = {}, aB[4] = {};
  int baseA = e0A, baseB = e0B;
  while (baseA < e1A || baseB < e1B) {
    int iA0 = baseA + g, iA1 = iA0 + 4, iA2 = iA0 + 8, iA3 = iA0 + 12;
    int iB0 = baseB + g, iB1 = iB0 + 4, iB2 = iB0 + 8, iB3 = iB0 + 12;
    int sA0 = edges[iA0 < e1A ? iA0 : lastA];
    int sA1 = edges[iA1 < e1A ? iA1 : lastA];
    int sA2 = edges[iA2 < e1A ? iA2 : lastA];
    int sA3 = edges[iA3 < e1A ? iA3 : lastA];
    int sB0 = edges[iB0 < e1B ? iB0 : lastB];
    int sB1 = edges[iB1 < e1B ? iB1 : lastB];
    int sB2 = edges[iB2 < e1B ? iB2 : lastB];
    int sB3 = edges[iB3 < e1B ? iB3 : lastB];
    sA0 = iA0 < e1A ? sA0 : n;   // zero row
    sA1 = iA1 < e1A ? sA1 : n;
    sA2 = iA2 < e1A ? sA2 : n;
    sA3 = iA3 < e1A ? sA3 : n;
    sB0 = iB0 < e1B ? sB0 : n;
    sB1 = iB1 < e1B ? sB1 : n;
    sB2 = iB2 < e1B ? sB2 : n;
    sB3 = iB3 < e1B ? sB3 : n;
    uint4 uA0 = *(const uint4*)&t[(size_t)sA0 * 128 + fl * 8];
    uint4 uA1 = *(const uint4*)&t[(size_t)sA1 * 128 + fl * 8];
    uint4 uA2 = *(const uint4*)&t[(size_t)sA2 * 128 + fl * 8];
    uint4 uA3 = *(const uint4*)&t[(size_t)sA3 * 128 + fl * 8];
    uint4 uB0 = *(const uint4*)&t[(size_t)sB0 * 128 + fl * 8];
    uint4 uB1 = *(const uint4*)&t[(size_t)sB1 * 128 + fl * 8];
    uint4 uB2 = *(const uint4*)&t[(size_t)sB2 * 128 + fl * 8];
    uint4 uB3 = *(const uint4*)&t[(size_t)sB3 * 128 + fl * 8];
    aA[0] = pkadd(aA[0], pkadd(pkadd(bfpair(uA0.x), bfpair(uA1.x)),
                               pkadd(bfpair(uA2.x), bfpair(uA3.x))));
    aA[1] = pkadd(aA[1], pkadd(pkadd(bfpair(uA0.y), bfpair(uA1.y)),
                               pkadd(bfpair(uA2.y), bfpair(uA3.y))));
    aA[2] = pkadd(aA[2], pkadd(pkadd(bfpair(uA0.z), bfpair(uA1.z)),
                               pkadd(bfpair(uA2.z), bfpair(uA3.z))));
    aA[3] = pkadd(aA[3], pkadd(pkadd(bfpair(uA0.w), bfpair(uA1.w)),
                               pkadd(bfpair(uA2.w), bfpair(uA3.w))));
    aB[0] = pkadd(aB[0], pkadd(pkadd(bfpair(uB0.x), bfpair(uB1.x)),
                               pkadd(bfpair(uB2.x), bfpair(uB3.x))));
    aB[1] = pkadd(aB[1], pkadd(pkadd(bfpair(uB0.y), bfpair(uB1.y)),
                               pkadd(bfpair(uB2.y), bfpair(uB3.y))));
    aB[2] = pkadd(aB[2], pkadd(pkadd(bfpair(uB0.z), bfpair(uB1.z)),
                               pkadd(bfpair(uB2.z), bfpair(uB3.z))));
    aB[3] = pkadd(aB[3], pkadd(pkadd(bfpair(uB0.w), bfpair(uB1.w)),
                               pkadd(bfpair(uB2.w), bfpair(uB3.w))));
    baseA += 16;
    baseB += 16;
  }
  float fA[8], fB[8];
#pragma unroll
  for (int j = 0; j < 4; ++j) {
    fA[2 * j] = aA[j].x; fA[2 * j + 1] = aA[j].y;
    fB[2 * j] = aB[j].x; fB[2 * j + 1] = aB[j].y;
  }
#pragma unroll
  for (int j = 0; j < 8; ++j) {
    fA[j] += __shfl_xor(fA[j], 16);
    fA[j] += __shfl_xor(fA[j], 32);
    fB[j] += __shfl_xor(fB[j], 16);
    fB[j] += __shfl_xor(fB[j], 32);
  }
  if (g == 0 || (g == 1 && hasB)) {
    float acc[8];
#pragma unroll
    for (int j = 0; j < 8; ++j) acc[j] = (g == 0) ? fA[j] : fB[j];
    acc[0] += bf_lo(sv.x); acc[1] += bf_hi(sv.x);
    acc[2] += bf_lo(sv.y); acc[3] += bf_hi(sv.y);
    acc[4] += bf_lo(sv.z); acc[5] += bf_hi(sv.z);
    acc[6] += bf_lo(sv.w); acc[7] += bf_hi(sv.w);
    float bb[8] = {bb0.x, bb0.y, bb0.z, bb0.w, bb1.x, bb1.y, bb1.z, bb1.w};
    short8 ho, lo_;
#pragma unroll
    for (int j = 0; j < 8; ++j) {
      float s = fmaxf(acc[j] * di + bb[j], 0.f);
      __bf16 h = (__bf16)s;
      ho[j] = __builtin_bit_cast(short, h);
      lo_[j] = (short)f2bf(s - (float)h);
    }
    *(short8*)&ghi[(size_t)nodeS * 128 + fl * 8] = ho;
    *(short8*)&glo[(size_t)nodeS * 128 + fl * 8] = lo_;
  }
}

extern "C" void kernel_launch(void* const* d_in, const int* in_sizes, int n_in,
                              void* d_out, int out_size, void* d_ws, size_t ws_size,
                              hipStream_t stream) {
  const float* x  = (const float*)d_in[0];
  const int*   ei = (const int*)d_in[1];
  const float* W1 = (const float*)d_in[2];
  const float* b1 = (const float*)d_in[3];
  const float* W2 = (const float*)d_in[4];
  const float* b2 = (const float*)d_in[5];
  const float* Wl = (const float*)d_in[6];
  const float* bl = (const float*)d_in[7];
  float* out = (float*)d_out;

  const int D = 128;
  int N = in_sizes[0] / D;
  int E = in_sizes[1] / 2;
  const int* src = ei;
  const int* dst = ei + E;

  uintptr_t ws = (uintptr_t)d_ws;
  auto take = [&](size_t bytes) {
    uintptr_t p = ws;
    ws += (bytes + 15) & ~(size_t)15;
    return p;
  };
  unsigned short* t_bf = (unsigned short*)take(((size_t)N + 1) * D * 2);  // + zero row
  unsigned short* xh   = (unsigned short*)take((size_t)N * D * 2);
  unsigned short* xl   = (unsigned short*)take((size_t)N * D * 2);
  unsigned short* edges = (unsigned short*)take((size_t)E * 2);  // u16 src ids
  int*   rank    = (int*)take((size_t)E * 4);
  int*   cnt     = (int*)take((size_t)N * sizeof(int));
  int*   row_off = (int*)take(((size_t)N + 2) * sizeof(int));
  float* dinv    = (float*)take((size_t)N * sizeof(float));
  int*   partial = (int*)take(256 * sizeof(int));
  unsigned short* b1h = (unsigned short*)take(128 * 128 * 2);
  unsigned short* b1l = (unsigned short*)take(128 * 128 * 2);
  unsigned short* b2h = (unsigned short*)take(128 * 128 * 2);
  unsigned short* b2l = (unsigned short*)take(128 * 128 * 2);
  unsigned short* blh = (unsigned short*)take(128 * 64 * 2);
  unsigned short* bll = (unsigned short*)take(128 * 64 * 2);

  int nb_n = (N + 255) / 256;   // 196 (fits single-block base reduce)
  int nb_e = (E + 255) / 256;

  // ---- graph preprocessing + weight prep ----
  hipMemsetAsync(cnt, 0, (size_t)N * sizeof(int), stream);
  k_count_prepW<<<nb_e + 160, 256, 0, stream>>>(dst, E, nb_e, cnt, rank,
                                                W1, W2, Wl, b1h, b1l, b2h, b2l, blh, bll);
  k_scan1<<<nb_n, 256, 0, stream>>>(cnt, N, partial, dinv);
  k_scan3<<<nb_n, 256, 0, stream>>>(cnt, partial, nb_n, N, row_off);
  k_place<<<nb_e, 256, 0, stream>>>(src, dst, rank, row_off, E, edges);

  int gemm_blocks = (N + 127) / 128;
  int agg_blocks = (N + 7) / 8;   // 2 nodes/wave, 4 waves/block

  // ---- layer 1 (A = fp32 x, split in-register; output pre-scaled by dinv) ----
  gemm3<8, true, false, true, true><<<gemm_blocks, 256, 0, stream>>>(
      x, nullptr, b1h, b1l, nullptr, dinv, t_bf, N);
  k_agg<<<agg_blocks, 256, 0, stream>>>(t_bf, row_off, edges, dinv, b1, xh, xl, N);
  // ---- layer 2 ----
  gemm3<8, false, false, true, true><<<gemm_blocks, 256, 0, stream>>>(
      xh, xl, b2h, b2l, nullptr, dinv, t_bf, N);
  k_agg<<<agg_blocks, 256, 0, stream>>>(t_bf, row_off, edges, dinv, b2, xh, xl, N);
  // ---- classifier ----
  gemm3<4, false, true, false, false><<<gemm_blocks, 256, 0, stream>>>(
      xh, xl, blh, bll, bl, nullptr, out, N);
}

// Round 9
// 229.110 us; speedup vs baseline: 1.0295x; 1.0284x over previous
//
#include <hip/hip_runtime.h>

// -------------------------------------------------------------------------
// GCN: h1 = relu(Agg(x@W1)+b1); h2 = relu(Agg(h1@W2)+b2); out = h2@Wl+bl
// R21 = exact R16 restored (228.8us session best) as final kernel.
// Plateau evidence (R17-R20 all regressed vs this base):
//   R17 feature-quarter planes  +22.7us (4x per-node fixed cost; counters:
//       agg VALUBusy~70%, HBM 14%, gathers cache-absorbed, 0 bank confl)
//   R18 branchless padded CSR + fp32 agg out  +3.4us (agg not
//       instruction-count-bound)
//   R19 gemm N-split (3 blk/CU)  +7.1us (gemm not latency-serialized)
//   R20 2-nodes/wave dual gather chains  +6.8us (VGPR 24->75 halved agg
//       occupancy; TLP loss > ILP gain)
// Agg floor arithmetic: E*16 = 11M independent 16B gather reqs/agg; at
// ~1 VMEM req/cyc/CU * 256 CU = ~18us issue floor/agg + index/reduce/store
// -> measured ~28us is within 1.5x of floor; 16B/lane is max granularity.
// Mechanisms in this kernel (all counter- or A/B-verified):
//   - gemm3: bf16x3-split MFMA (hi*hi+hi*lo+lo*hi, ~2^-17 rel err),
//     swapped-operand mfma(b,a,acc) -> C^T acc layout (lane=C-row, regs=4
//     consecutive C-cols) -> packed 8B/16B epilogue stores; B hi+lo staged
//     in LDS XOR-swizzled (R13: streaming Blo from global = -5us); A frags
//     prefetched; dinv row-scaling + zero-row write fused into epilogue.
//   - k_agg: 4 nodes/block, 16 edges in flight, u16 edge ids, hoisted
//     epilogue loads, v_pk_add_f32 accumulation tree.
//   - CSR build: rank captured from count's atomicAdd return; place is
//     atomic-free; prepW fused into count dispatch; dinv fused into scan1.
// -------------------------------------------------------------------------

typedef __attribute__((ext_vector_type(8))) __bf16 bf16x8;
typedef __attribute__((ext_vector_type(8))) short short8;
typedef __attribute__((ext_vector_type(4))) float f32x4;
typedef __attribute__((ext_vector_type(2))) float f32x2;

__device__ inline float bf_lo(unsigned u) { return __uint_as_float(u << 16); }
__device__ inline float bf_hi(unsigned u) { return __uint_as_float(u & 0xffff0000u); }
__device__ inline unsigned short f2bf(float v) {
  return __builtin_bit_cast(unsigned short, (__bf16)v);
}
// packed 2xf32 add (VOP3P)
__device__ inline f32x2 pkadd(f32x2 a, f32x2 b) {
  f32x2 d;
  asm("v_pk_add_f32 %0, %1, %2" : "=v"(d) : "v"(a), "v"(b));
  return d;
}
// bf16 pair word -> float2 {low half, high half}
__device__ inline f32x2 bfpair(unsigned w) {
  f32x2 r;
  r.x = __uint_as_float(w << 16);
  r.y = __uint_as_float(w & 0xffff0000u);
  return r;
}

// fat kernel: blocks [0, nbe) count in-degrees + capture rank;
// blocks [nbe, nbe+160) split/transpose weights to bf16 hi/lo
__global__ void k_count_prepW(const int* __restrict__ dst, int E, int nbe,
                              int* __restrict__ cnt, int* __restrict__ rank,
                              const float* __restrict__ W1, const float* __restrict__ W2,
                              const float* __restrict__ Wl,
                              unsigned short* __restrict__ b1h, unsigned short* __restrict__ b1l,
                              unsigned short* __restrict__ b2h, unsigned short* __restrict__ b2l,
                              unsigned short* __restrict__ blh, unsigned short* __restrict__ bll) {
  if ((int)blockIdx.x < nbe) {
    int i = blockIdx.x * 256 + threadIdx.x;
    if (i < E) rank[i] = atomicAdd(&cnt[dst[i]], 1);
  } else {
    int idx = ((int)blockIdx.x - nbe) * 256 + threadIdx.x;
    const float* W;
    unsigned short *bh, *bl_;
    int N, local;
    if (idx < 16384)      { W = W1; bh = b1h; bl_ = b1l; N = 128; local = idx; }
    else if (idx < 32768) { W = W2; bh = b2h; bl_ = b2l; N = 128; local = idx - 16384; }
    else if (idx < 40960) { W = Wl; bh = blh; bl_ = bll; N = 64;  local = idx - 32768; }
    else return;
    int nn = local >> 7, k = local & 127;
    float v = W[(size_t)k * N + nn];
    __bf16 h = (__bf16)v;
    bh[local] = __builtin_bit_cast(unsigned short, h);
    bl_[local] = f2bf(v - (float)h);
  }
}

// scan1: per-block partial sums of cnt; also dinv = rsqrt(deg+1)
__global__ void k_scan1(const int* __restrict__ cnt, int n, int* __restrict__ partial,
                        float* __restrict__ dinv) {
  __shared__ int s[256];
  int i = blockIdx.x * 256 + threadIdx.x;
  int v = (i < n) ? cnt[i] : 0;
  s[threadIdx.x] = v;
  if (i < n) dinv[i] = rsqrtf((float)(v + 1));
  __syncthreads();
  for (int off = 128; off > 0; off >>= 1) {
    if (threadIdx.x < off) s[threadIdx.x] += s[threadIdx.x + off];
    __syncthreads();
  }
  if (threadIdx.x == 0) partial[blockIdx.x] = s[0];
}

// scan3: block base from partials + exclusive scan -> row_off
__global__ void k_scan3(const int* __restrict__ cnt, const int* __restrict__ partial,
                        int nb, int n, int* __restrict__ row_off) {
  __shared__ int s[256];
  __shared__ int base_s;
  int t = threadIdx.x;
  s[t] = (t < nb && t < (int)blockIdx.x) ? partial[t] : 0;
  __syncthreads();
  for (int off = 128; off > 0; off >>= 1) {
    if (t < off) s[t] += s[t + off];
    __syncthreads();
  }
  if (t == 0) base_s = s[0];
  __syncthreads();
  int base = base_s;
  __syncthreads();

  int i = blockIdx.x * 256 + t;
  int v = (i < n) ? cnt[i] : 0;
  s[t] = v;
  __syncthreads();
  for (int off = 1; off < 256; off <<= 1) {
    int u = (t >= off) ? s[t - off] : 0;
    __syncthreads();
    s[t] += u;
    __syncthreads();
  }
  int incl = s[t];
  int excl = incl - v;
  if (i < n) {
    row_off[i] = base + excl;
    if (i == n - 1) row_off[n] = base + incl;
  }
}

// place: NO atomics -- pos = row_off[dst] + rank; edges stored as u16
__global__ void k_place(const int* __restrict__ src, const int* __restrict__ dst,
                        const int* __restrict__ rank, const int* __restrict__ row_off,
                        int E, unsigned short* __restrict__ edges) {
  int e = blockIdx.x * blockDim.x + threadIdx.x;
  if (e < E) {
    int d = dst[e];
    int pos = row_off[d] + rank[e];
    __builtin_nontemporal_store((unsigned short)src[e], &edges[pos]);
  }
}

// ------------------- MFMA GEMM: A prefetched, B (hi+lo) in LDS -----------
// C[M x N] = A[M x 128] @ B[128 x N], N = NT*16.
// Operand-SWAPPED mfma: acc = mfma(b_frag, a_frag, acc) computes C^T tile
// layout: per lane, C-row = m_base+mt*16+lm, C-cols = nt*16+lk*4+r (r=0..3)
// -> packed 8B/16B epilogue stores.
// SCALE: multiply output row r by dinv[r] and write zero row M (agg OOB).
template <int NT, bool A32, bool BIAS, bool OUT_BF16, bool SCALE>
__global__ __launch_bounds__(256) void gemm3(
    const void* __restrict__ Ahi_, const unsigned short* __restrict__ Alo,
    const unsigned short* __restrict__ Bhi, const unsigned short* __restrict__ Blo,
    const float* __restrict__ bias, const float* __restrict__ dinv,
    void* __restrict__ Cout, int M) {
  constexpr int K = 128;
  constexpr int NCOL = NT * 16;
  __shared__ alignas(16) unsigned short lbh[NCOL * K];
  __shared__ alignas(16) unsigned short lbl[NCOL * K];
  int t = threadIdx.x;
  int lane = t & 63, wave = t >> 6;
  int lm = lane & 15, lk = lane >> 4;
  int m_base = blockIdx.x * 128 + wave * 32;
  const short8 zero8 = {0, 0, 0, 0, 0, 0, 0, 0};

  if (SCALE && blockIdx.x == 0 && t < 64) {   // zero row M for agg OOB lanes
    *(unsigned*)&((unsigned short*)Cout)[(size_t)M * NCOL + t * 2] = 0u;
  }

  // ---- phase 1: prefetch all A fragments ----
  bf16x8 ah[2][4], al[2][4];
  if (A32) {
    const float* Af = (const float*)Ahi_;
    float4 ra[2][4][2];
#pragma unroll
    for (int mt = 0; mt < 2; ++mt) {
      int row = m_base + mt * 16 + lm;
#pragma unroll
      for (int ks = 0; ks < 4; ++ks) {
        if (row < M) {
          ra[mt][ks][0] = *(const float4*)&Af[(size_t)row * K + ks * 32 + lk * 8];
          ra[mt][ks][1] = *(const float4*)&Af[(size_t)row * K + ks * 32 + lk * 8 + 4];
        } else {
          ra[mt][ks][0] = make_float4(0.f, 0.f, 0.f, 0.f);
          ra[mt][ks][1] = make_float4(0.f, 0.f, 0.f, 0.f);
        }
      }
    }
#pragma unroll
    for (int mt = 0; mt < 2; ++mt)
#pragma unroll
      for (int ks = 0; ks < 4; ++ks) {
        float av[8] = {ra[mt][ks][0].x, ra[mt][ks][0].y, ra[mt][ks][0].z, ra[mt][ks][0].w,
                       ra[mt][ks][1].x, ra[mt][ks][1].y, ra[mt][ks][1].z, ra[mt][ks][1].w};
#pragma unroll
        for (int j = 0; j < 8; ++j) {
          __bf16 h = (__bf16)av[j];
          ah[mt][ks][j] = h;
          al[mt][ks][j] = (__bf16)(av[j] - (float)h);
        }
      }
  } else {
    const unsigned short* Ahi = (const unsigned short*)Ahi_;
#pragma unroll
    for (int mt = 0; mt < 2; ++mt) {
      int row = m_base + mt * 16 + lm;
#pragma unroll
      for (int ks = 0; ks < 4; ++ks) {
        if (row < M) {
          ah[mt][ks] = *(const bf16x8*)&Ahi[(size_t)row * K + ks * 32 + lk * 8];
          al[mt][ks] = *(const bf16x8*)&Alo[(size_t)row * K + ks * 32 + lk * 8];
        } else {
          ah[mt][ks] = __builtin_bit_cast(bf16x8, zero8);
          al[mt][ks] = __builtin_bit_cast(bf16x8, zero8);
        }
      }
    }
  }

  // ---- phase 2: cooperative B staging (XOR-swizzled 16B chunks) ----
  for (int c = t; c < NCOL * 16; c += 256) {
    int r = c >> 4, q = c & 15;
    int sq = q ^ (r & 15);
    *(short8*)&lbh[r * K + sq * 8] = *(const short8*)&Bhi[r * K + q * 8];
    *(short8*)&lbl[r * K + sq * 8] = *(const short8*)&Blo[r * K + q * 8];
  }
  __syncthreads();

  // ---- phase 3: pure LDS + MFMA, swapped operands ----
  f32x4 acc[2][NT] = {};
#pragma unroll
  for (int ks = 0; ks < 4; ++ks) {
    int chunk = ks * 4 + lk;
    bf16x8 bh[NT], bl[NT];
#pragma unroll
    for (int nt = 0; nt < NT; ++nt) {
      int r = nt * 16 + lm;
      int sq = chunk ^ lm;
      bh[nt] = *(const bf16x8*)&lbh[r * K + sq * 8];
      bl[nt] = *(const bf16x8*)&lbl[r * K + sq * 8];
    }
#pragma unroll
    for (int mt = 0; mt < 2; ++mt)
#pragma unroll
      for (int nt = 0; nt < NT; ++nt) {
        acc[mt][nt] = __builtin_amdgcn_mfma_f32_16x16x32_bf16(bh[nt], ah[mt][ks], acc[mt][nt], 0, 0, 0);
        acc[mt][nt] = __builtin_amdgcn_mfma_f32_16x16x32_bf16(bl[nt], ah[mt][ks], acc[mt][nt], 0, 0, 0);
        acc[mt][nt] = __builtin_amdgcn_mfma_f32_16x16x32_bf16(bh[nt], al[mt][ks], acc[mt][nt], 0, 0, 0);
      }
  }

  // ---- epilogue (transposed acc): row = m_base+mt*16+lm, cols = nt*16+lk*4+r
#pragma unroll
  for (int mt = 0; mt < 2; ++mt) {
    int row = m_base + mt * 16 + lm;
    if (row < M) {
      float dr = SCALE ? dinv[row] : 1.f;
#pragma unroll
      for (int nt = 0; nt < NT; ++nt) {
        int col0 = nt * 16 + lk * 4;
        float v0 = acc[mt][nt][0], v1 = acc[mt][nt][1];
        float v2 = acc[mt][nt][2], v3 = acc[mt][nt][3];
        if (SCALE) { v0 *= dr; v1 *= dr; v2 *= dr; v3 *= dr; }
        if (BIAS) {
          float4 bb = *(const float4*)&bias[col0];
          v0 += bb.x; v1 += bb.y; v2 += bb.z; v3 += bb.w;
        }
        if (OUT_BF16) {
          unsigned p0 = (unsigned)f2bf(v0) | ((unsigned)f2bf(v1) << 16);
          unsigned p1 = (unsigned)f2bf(v2) | ((unsigned)f2bf(v3) << 16);
          uint2 pk = make_uint2(p0, p1);
          *(uint2*)&((unsigned short*)Cout)[(size_t)row * NCOL + col0] = pk;
        } else {
          float4 pk = make_float4(v0, v1, v2, v3);
          *(float4*)&((float*)Cout)[(size_t)row * NCOL + col0] = pk;
        }
      }
    }
  }
}

// ------------------- aggregation: 16 edges in flight, u16 edges ----------
// rows pre-scaled by dinv[src]; agg_i = dinv_i*(sum + self) + bias, relu.
// OOB edge slots read zero row M (index n).
// Hot loop accumulates in float2 via v_pk_add_f32.
__global__ __launch_bounds__(256) void k_agg(const unsigned short* __restrict__ t,
                      const int* __restrict__ row_off,
                      const unsigned short* __restrict__ edges,
                      const float* __restrict__ dinv, const float* __restrict__ bias,
                      unsigned short* __restrict__ ghi, unsigned short* __restrict__ glo,
                      int n) {
  int wave = threadIdx.x >> 6;
  int lane = threadIdx.x & 63;
  int g = lane >> 4;
  int fl = lane & 15;          // features fl*8 .. fl*8+7
  int node = blockIdx.x * 4 + wave;
  if (node >= n) return;
  int2 ro = *(const int2*)&row_off[node];
  int e0 = ro.x, e1 = ro.y;
  int last = e1 - 1;

  // hoisted epilogue loads: overlap with gather chain
  float di = dinv[node];
  uint4 sv = *(const uint4*)&t[(size_t)node * 128 + fl * 8];
  float4 bb0 = *(const float4*)&bias[fl * 8];
  float4 bb1 = *(const float4*)&bias[fl * 8 + 4];

  f32x2 acc2[4] = {};
  for (int base = e0; base < e1; base += 16) {
    int i0 = base + g, i1 = i0 + 4, i2 = i0 + 8, i3 = i0 + 12;
    int s0 = edges[i0 < e1 ? i0 : last];
    int s1 = edges[i1 < e1 ? i1 : last];
    int s2 = edges[i2 < e1 ? i2 : last];
    int s3 = edges[i3 < e1 ? i3 : last];
    s0 = i0 < e1 ? s0 : n;     // zero row
    s1 = i1 < e1 ? s1 : n;
    s2 = i2 < e1 ? s2 : n;
    s3 = i3 < e1 ? s3 : n;
    uint4 u0 = *(const uint4*)&t[(size_t)s0 * 128 + fl * 8];
    uint4 u1 = *(const uint4*)&t[(size_t)s1 * 128 + fl * 8];
    uint4 u2 = *(const uint4*)&t[(size_t)s2 * 128 + fl * 8];
    uint4 u3 = *(const uint4*)&t[(size_t)s3 * 128 + fl * 8];
    acc2[0] = pkadd(acc2[0], pkadd(pkadd(bfpair(u0.x), bfpair(u1.x)),
                                   pkadd(bfpair(u2.x), bfpair(u3.x))));
    acc2[1] = pkadd(acc2[1], pkadd(pkadd(bfpair(u0.y), bfpair(u1.y)),
                                   pkadd(bfpair(u2.y), bfpair(u3.y))));
    acc2[2] = pkadd(acc2[2], pkadd(pkadd(bfpair(u0.z), bfpair(u1.z)),
                                   pkadd(bfpair(u2.z), bfpair(u3.z))));
    acc2[3] = pkadd(acc2[3], pkadd(pkadd(bfpair(u0.w), bfpair(u1.w)),
                                   pkadd(bfpair(u2.w), bfpair(u3.w))));
  }
  float acc[8];
#pragma unroll
  for (int j = 0; j < 4; ++j) { acc[2 * j] = acc2[j].x; acc[2 * j + 1] = acc2[j].y; }
#pragma unroll
  for (int j = 0; j < 8; ++j) {
    acc[j] += __shfl_xor(acc[j], 16);
    acc[j] += __shfl_xor(acc[j], 32);
  }
  if (g == 0) {
    acc[0] += bf_lo(sv.x); acc[1] += bf_hi(sv.x);
    acc[2] += bf_lo(sv.y); acc[3] += bf_hi(sv.y);
    acc[4] += bf_lo(sv.z); acc[5] += bf_hi(sv.z);
    acc[6] += bf_lo(sv.w); acc[7] += bf_hi(sv.w);
    float bb[8] = {bb0.x, bb0.y, bb0.z, bb0.w, bb1.x, bb1.y, bb1.z, bb1.w};
    short8 ho, lo_;
#pragma unroll
    for (int j = 0; j < 8; ++j) {
      float s = fmaxf(acc[j] * di + bb[j], 0.f);
      __bf16 h = (__bf16)s;
      ho[j] = __builtin_bit_cast(short, h);
      lo_[j] = (short)f2bf(s - (float)h);
    }
    *(short8*)&ghi[(size_t)node * 128 + fl * 8] = ho;
    *(short8*)&glo[(size_t)node * 128 + fl * 8] = lo_;
  }
}

extern "C" void kernel_launch(void* const* d_in, const int* in_sizes, int n_in,
                              void* d_out, int out_size, void* d_ws, size_t ws_size,
                              hipStream_t stream) {
  const float* x  = (const float*)d_in[0];
  const int*   ei = (const int*)d_in[1];
  const float* W1 = (const float*)d_in[2];
  const float* b1 = (const float*)d_in[3];
  const float* W2 = (const float*)d_in[4];
  const float* b2 = (const float*)d_in[5];
  const float* Wl = (const float*)d_in[6];
  const float* bl = (const float*)d_in[7];
  float* out = (float*)d_out;

  const int D = 128;
  int N = in_sizes[0] / D;
  int E = in_sizes[1] / 2;
  const int* src = ei;
  const int* dst = ei + E;

  uintptr_t ws = (uintptr_t)d_ws;
  auto take = [&](size_t bytes) {
    uintptr_t p = ws;
    ws += (bytes + 15) & ~(size_t)15;
    return p;
  };
  unsigned short* t_bf = (unsigned short*)take(((size_t)N + 1) * D * 2);  // + zero row
  unsigned short* xh   = (unsigned short*)take((size_t)N * D * 2);
  unsigned short* xl   = (unsigned short*)take((size_t)N * D * 2);
  unsigned short* edges = (unsigned short*)take((size_t)E * 2);  // u16 src ids
  int*   rank    = (int*)take((size_t)E * 4);
  int*   cnt     = (int*)take((size_t)N * sizeof(int));
  int*   row_off = (int*)take(((size_t)N + 1) * sizeof(int));
  float* dinv    = (float*)take((size_t)N * sizeof(float));
  int*   partial = (int*)take(256 * sizeof(int));
  unsigned short* b1h = (unsigned short*)take(128 * 128 * 2);
  unsigned short* b1l = (unsigned short*)take(128 * 128 * 2);
  unsigned short* b2h = (unsigned short*)take(128 * 128 * 2);
  unsigned short* b2l = (unsigned short*)take(128 * 128 * 2);
  unsigned short* blh = (unsigned short*)take(128 * 64 * 2);
  unsigned short* bll = (unsigned short*)take(128 * 64 * 2);

  int nb_n = (N + 255) / 256;   // 196 (fits single-block base reduce)
  int nb_e = (E + 255) / 256;

  // ---- graph preprocessing + weight prep ----
  hipMemsetAsync(cnt, 0, (size_t)N * sizeof(int), stream);
  k_count_prepW<<<nb_e + 160, 256, 0, stream>>>(dst, E, nb_e, cnt, rank,
                                                W1, W2, Wl, b1h, b1l, b2h, b2l, blh, bll);
  k_scan1<<<nb_n, 256, 0, stream>>>(cnt, N, partial, dinv);
  k_scan3<<<nb_n, 256, 0, stream>>>(cnt, partial, nb_n, N, row_off);
  k_place<<<nb_e, 256, 0, stream>>>(src, dst, rank, row_off, E, edges);

  int gemm_blocks = (N + 127) / 128;
  int agg_blocks = (N + 3) / 4;

  // ---- layer 1 (A = fp32 x, split in-register; output pre-scaled by dinv) ----
  gemm3<8, true, false, true, true><<<gemm_blocks, 256, 0, stream>>>(
      x, nullptr, b1h, b1l, nullptr, dinv, t_bf, N);
  k_agg<<<agg_blocks, 256, 0, stream>>>(t_bf, row_off, edges, dinv, b1, xh, xl, N);
  // ---- layer 2 ----
  gemm3<8, false, false, true, true><<<gemm_blocks, 256, 0, stream>>>(
      xh, xl, b2h, b2l, nullptr, dinv, t_bf, N);
  k_agg<<<agg_blocks, 256, 0, stream>>>(t_bf, row_off, edges, dinv, b2, xh, xl, N);
  // ---- classifier ----
  gemm3<4, false, true, false, false><<<gemm_blocks, 256, 0, stream>>>(
      xh, xl, blh, bll, bl, nullptr, out, N);
}